// Round 11
// baseline (119.719 us; speedup 1.0000x reference)
//
#include <hip/hip_runtime.h>

#define B_N 4096
#define M_N 3
#define D_N 256
#define LOG2E 1.44269504088896340736f
#define LN2   0.69314718055994530942f
#define C_OFF 64.0f

typedef __bf16 bf16x8 __attribute__((ext_vector_type(8)));
typedef float  f32x4  __attribute__((ext_vector_type(4)));

__device__ __forceinline__ unsigned short f2bf(float f) {
    unsigned int u = __float_as_uint(f);
    u += 0x7FFFu + ((u >> 16) & 1u);   // round-to-nearest-even
    return (unsigned short)(u >> 16);
}
__device__ __forceinline__ float bf2f(unsigned short h) {
    return __uint_as_float(((unsigned int)h) << 16);
}

// tokens [i][m][d] f32 -> tokb [m][i][d] bf16
__global__ void cvt_kernel(const float* __restrict__ in, unsigned short* __restrict__ out) {
    int idx = blockIdx.x * 256 + threadIdx.x;   // 786432 float4s
    float4 v = reinterpret_cast<const float4*>(in)[idx];
    int i   = idx / 192;            // 192 = M*D/4
    int rem = idx - i * 192;
    int m   = rem >> 6;
    int d4  = rem & 63;
    ushort4 o;
    o.x = f2bf(v.x); o.y = f2bf(v.y); o.z = f2bf(v.z); o.w = f2bf(v.w);
    reinterpret_cast<ushort4*>(out)[((size_t)m * B_N + i) * 64 + d4] = o;
}

// Partial label centroids. 48 blocks = 3m x 16 parts x 256 rows.
// Thread d owns column d exclusively -> plain LDS RMW (no atomics); 16
// register-staged loads per batch so each latency wait covers 16 rows.
__global__ __launch_bounds__(256) void cent1_kernel(const float* __restrict__ tokens,
                                                    const int* __restrict__ labels,
                                                    unsigned short* __restrict__ cpart) {
    int m = blockIdx.x >> 4, part = blockIdx.x & 15;
    int d = threadIdx.x;
    __shared__ float Cl[32 * 256];
    __shared__ int labl[256];
#pragma unroll
    for (int q = 0; q < 32; ++q) Cl[q * 256 + d] = 0.f;
    int rbase = part * 256;
    labl[d] = labels[rbase + d];
    __syncthreads();
    const float* src = tokens + ((size_t)rbase * 3 + m) * 256 + d;
    for (int r = 0; r < 256; r += 16) {
        float xv[16];
#pragma unroll
        for (int u = 0; u < 16; ++u) xv[u] = src[(size_t)(r + u) * 768];
#pragma unroll
        for (int u = 0; u < 16; ++u) Cl[labl[r + u] * 256 + d] += xv[u];  // exclusive: no race
    }
    __syncthreads();
    unsigned short* dst = cpart + (size_t)(m * 16 + part) * 8192;
#pragma unroll
    for (int q = 0; q < 32; ++q) dst[q * 256 + d] = f2bf(Cl[q * 256 + d]);
}

// Merge 16 bf16 partial centroids -> f32 centroid[m][lab][d]; block 0: hist+nv.
__global__ void cent2_kernel(const unsigned short* __restrict__ cpart,
                             float* __restrict__ centroid,
                             const int* __restrict__ labels, int* __restrict__ hist,
                             int* __restrict__ nvout) {
    int g = blockIdx.x * 1024 + threadIdx.x;   // 24576 outputs
    int m = g >> 13, r = g & 8191;
    const unsigned short* cp = cpart + (size_t)m * 16 * 8192 + r;
    float s = 0.f;
#pragma unroll
    for (int p = 0; p < 16; ++p) s += bf2f(cp[p * 8192]);
    centroid[g] = s;
    if (blockIdx.x == 0) {
        __shared__ int h[32];
        int tid = threadIdx.x;
        if (tid < 32) h[tid] = 0;
        __syncthreads();
        for (int i = tid; i < B_N; i += 1024) atomicAdd(&h[labels[i]], 1);
        __syncthreads();
        if (tid < 32) hist[tid] = h[tid];
        if (tid == 0) {
            int nv = 0;
#pragma unroll
            for (int c = 0; c < 32; ++c) nv += (h[c] >= 2) ? h[c] : 0;
            nvout[0] = nv;
        }
    }
}

// Block: 256 rows x 256 cols of one modality; 4 waves x 64 rows (rt=4).
// Per phase: 16-col x 256-d B tile (8 KB) in double-buffered LDS, staged
// global->reg->ds_write with the verified XOR swizzle; label-free epilogue.
// grid = 3m x 16ns x 16rb = 768 blocks = EXACTLY 3/CU co-resident (single
// batch, 3 independent barrier groups interleave per CU -- the r4-proven
// occupancy that hides the per-phase stage/barrier stall).
__global__ __launch_bounds__(256, 3) void main_kernel(
    const unsigned short* __restrict__ tokb, float* __restrict__ partialsS) {
    int raw = blockIdx.x;
    int bid = (raw & 7) * 96 + (raw >> 3);   // bijective XCD swizzle (768 % 8 == 0)
    int m  = bid >> 8;
    int ns = (bid >> 4) & 15;
    int rb = bid & 15;
    int i0 = rb * 256;
    int cb = ns * 256;

    int tid  = threadIdx.x;
    int wave = tid >> 6, lane = tid & 63;
    int lr = lane & 15, lk = lane >> 4;
    const unsigned short* tm = tokb + (size_t)m * (B_N * D_N);

    __shared__ __align__(16) char ldsB[2][8192];

    // A fragments: rows r0 + rt*16 + lr, registers for whole kernel
    int r0 = i0 + wave * 64;
    bf16x8 afrag[4][8];
#pragma unroll
    for (int rt = 0; rt < 4; ++rt) {
        const unsigned short* rp = tm + (size_t)(r0 + rt * 16 + lr) * D_N + lk * 8;
#pragma unroll
        for (int kf = 0; kf < 8; ++kf)
            afrag[rt][kf] = *reinterpret_cast<const bf16x8*>(rp + kf * 32);
    }

    float S[4][4];
#pragma unroll
    for (int rt = 0; rt < 4; ++rt)
#pragma unroll
        for (int j = 0; j < 4; ++j) S[rt][j] = 0.f;

    // Staging map (verified rounds 4-10): thread (lc = tid>>5, w = tid&31)
    // loads source chunk sch = w ^ (lc&7) of cols (cb+lc),(cb+lc+8); writes
    // LDS linearly at tid*16 / 4096+tid*16. Reads apply the same XOR.
    int lc  = tid >> 5;
    int w   = tid & 31;
    int sch = w ^ (lc & 7);
    const unsigned short* sbase = tm + (size_t)(cb + lc) * D_N + sch * 8;

    // prologue: tile 0 -> buf0
    {
        bf16x8 t0 = *reinterpret_cast<const bf16x8*>(sbase);
        bf16x8 t1 = *reinterpret_cast<const bf16x8*>(sbase + 8 * D_N);
        *reinterpret_cast<bf16x8*>(&ldsB[0][tid * 16])        = t0;
        *reinterpret_cast<bf16x8*>(&ldsB[0][4096 + tid * 16]) = t1;
    }

    for (int kb = 0; kb < 16; ++kb) {
        int cur = kb & 1;
        __syncthreads();   // buf[cur] staged; all prior reads of buf[cur^1] done

        // next-tile loads at phase top; compute covers their latency (r4 pattern)
        const unsigned short* np = sbase + (size_t)((kb + 1) & 15) * (16 * D_N);
        bf16x8 nt0 = *reinterpret_cast<const bf16x8*>(np);
        bf16x8 nt1 = *reinterpret_cast<const bf16x8*>(np + 8 * D_N);

        const char* bp = ldsB[cur];
        int swz = (lr & 7) << 4;
        bf16x8 bfrag[8];
#pragma unroll
        for (int kf = 0; kf < 8; ++kf)
            bfrag[kf] = *reinterpret_cast<const bf16x8*>(
                bp + lr * 512 + (((kf * 4 + lk) << 4) ^ swz));

        f32x4 acc[4];
#pragma unroll
        for (int rt = 0; rt < 4; ++rt) acc[rt] = f32x4{0.f, 0.f, 0.f, 0.f};
#pragma unroll
        for (int kf = 0; kf < 8; ++kf) {
#pragma unroll
            for (int rt = 0; rt < 4; ++rt)
                acc[rt] = __builtin_amdgcn_mfma_f32_16x16x32_bf16(
                    afrag[rt][kf], bfrag[kf], acc[rt], 0, 0, 0);
        }

        int cg0 = cb + kb * 16;
        if ((cg0 < r0 + 64) && (cg0 + 16 > r0)) {
            int colg = cg0 + lr;
#pragma unroll
            for (int rt = 0; rt < 4; ++rt) {
#pragma unroll
                for (int j = 0; j < 4; ++j) {
                    float e = __builtin_amdgcn_exp2f(fmaf(acc[rt][j], LOG2E, -C_OFF));
                    int row = r0 + rt * 16 + lk * 4 + j;
                    S[rt][j] += (colg == row) ? 0.f : e;  // diag Inf discarded by select
                }
            }
        } else {
#pragma unroll
            for (int rt = 0; rt < 4; ++rt) {
#pragma unroll
                for (int j = 0; j < 4; ++j)
                    S[rt][j] += __builtin_amdgcn_exp2f(fmaf(acc[rt][j], LOG2E, -C_OFF));
            }
        }

        // write next tile to other buffer; barrier at loop top publishes it
        *reinterpret_cast<bf16x8*>(&ldsB[cur ^ 1][tid * 16])        = nt0;
        *reinterpret_cast<bf16x8*>(&ldsB[cur ^ 1][4096 + tid * 16]) = nt1;
    }

    // sum across the 16 col-lanes (lanes sharing lk hold the same rows)
#pragma unroll
    for (int rt = 0; rt < 4; ++rt)
#pragma unroll
        for (int j = 0; j < 4; ++j) {
            float sv = S[rt][j];
#pragma unroll
            for (int msk = 1; msk < 16; msk <<= 1) sv += __shfl_xor(sv, msk);
            if (lr == 0) {
                int rl = wave * 64 + rt * 16 + lk * 4 + j;
                partialsS[(size_t)((m * 16 + rb) * 16 + ns) * 256 + rl] = sv;
            }
        }
}

// one wave per (i,m): P via centroid dot (exact f32), merge 16 S partials,
// finish loss term, atomically accumulate into out (final_kernel fused).
__global__ void reduce_kernel(const float* __restrict__ partialsS,
                              const float* __restrict__ tokens,
                              const int* __restrict__ labels,
                              const float* __restrict__ centroid,
                              const int* __restrict__ hist,
                              const int* __restrict__ nvp,
                              float* __restrict__ out) {
    int tid = threadIdx.x;
    int wave = tid >> 6, lane = tid & 63;
    int gw = blockIdx.x * 4 + wave;      // 0..12287
    int m = gw >> 12, i = gw & 4095;
    int lab = labels[i];

    float4 x = *reinterpret_cast<const float4*>(tokens + ((size_t)i * 3 + m) * 256 + (lane << 2));
    float4 c = *reinterpret_cast<const float4*>(centroid + ((size_t)m * 32 + lab) * 256 + (lane << 2));
    float dotC = x.x * c.x + x.y * c.y + x.z * c.z + x.w * c.w;
    float dotX = x.x * x.x + x.y * x.y + x.z * x.z + x.w * x.w;
#pragma unroll
    for (int msk = 1; msk < 64; msk <<= 1) {
        dotC += __shfl_xor(dotC, msk);
        dotX += __shfl_xor(dotX, msk);
    }

    int rb = i >> 8, r = i & 255;
    const float* sp = partialsS + (size_t)((m * 16 + rb) * 16) * 256 + r;
    float Ssum = (lane < 16) ? sp[lane * 256] : 0.f;
#pragma unroll
    for (int msk = 1; msk < 16; msk <<= 1) Ssum += __shfl_xor(Ssum, msk);

    __shared__ float w4[4];
    if (lane == 0) {
        int pc = hist[lab] - 1;
        float contrib = (pc > 0)
            ? (__builtin_amdgcn_logf(Ssum) + C_OFF) * LN2 - (dotC - dotX) / (float)pc
            : 0.f;
        w4[wave] = contrib;
    }
    __syncthreads();
    if (tid == 0)
        atomicAdd(out, (w4[0] + w4[1] + w4[2] + w4[3]) / (float)(nvp[0] * M_N));
}

extern "C" void kernel_launch(void* const* d_in, const int* in_sizes, int n_in,
                              void* d_out, int out_size, void* d_ws, size_t ws_size,
                              hipStream_t stream) {
    const float* tokens = (const float*)d_in[0];
    const int*   labels = (const int*)d_in[1];
    float* out = (float*)d_out;

    char* ws = (char*)d_ws;
    int*   hist      = (int*)ws;                            // 32 ints @ 0
    int*   nv        = (int*)(ws + 128);                    // 1 int
    // Region X @16384 (786432 B), stream-ordered overlay:
    //   cpart bf16 (3*16*8192*2 = 786432 B): cent1 writes, cent2 reads (pre-main)
    //   partialsS f32 (786432 B): main writes, reduce reads
    unsigned short* cpart = (unsigned short*)(ws + 16384);
    float* partialsS = (float*)(ws + 16384);
    float* centroid  = (float*)(ws + 802816);               // 98304 B, ends 901120
    unsigned short* tokb = (unsigned short*)(ws + 901120);  // 6.29 MB, ends 7.19 MB

    hipMemsetAsync(d_out, 0, sizeof(float), stream);        // reduce accumulates into out
    cvt_kernel<<<3072, 256, 0, stream>>>(tokens, tokb);
    cent1_kernel<<<48, 256, 0, stream>>>(tokens, labels, cpart);
    cent2_kernel<<<24, 1024, 0, stream>>>(cpart, centroid, labels, hist, nv);
    main_kernel<<<768, 256, 0, stream>>>(tokb, partialsS);
    reduce_kernel<<<3072, 256, 0, stream>>>(partialsS, tokens, labels, centroid, hist, nv, out);
}

// Round 12
// 54.887 us; speedup vs baseline: 2.1812x; 2.1812x over previous
//
#include <hip/hip_runtime.h>

#define B_N 4096
#define M_N 3
#define D_N 256
#define LOG2E 1.44269504088896340736f
#define LN2   0.69314718055994530942f
#define C_OFF   64.0f
#define T_CLAMP 112.0f

typedef __bf16 bf16x8 __attribute__((ext_vector_type(8)));
typedef float  f32x4  __attribute__((ext_vector_type(4)));

__device__ __forceinline__ unsigned short f2bf(float f) {
    unsigned int u = __float_as_uint(f);
    u += 0x7FFFu + ((u >> 16) & 1u);   // round-to-nearest-even
    return (unsigned short)(u >> 16);
}
__device__ __forceinline__ float bf2f(unsigned short h) {
    return __uint_as_float(((unsigned int)h) << 16);
}

// tokens [i][m][d] f32 -> tokb [m][i][d] bf16; norm2[m*B+i] = sum(bf16(x)^2)
__global__ void cvt_kernel(const float* __restrict__ in, unsigned short* __restrict__ out,
                           float* __restrict__ norm2) {
    int idx = blockIdx.x * blockDim.x + threadIdx.x;   // 786432 float4s
    float4 v = reinterpret_cast<const float4*>(in)[idx];
    int i   = idx / 192;            // 192 = M*D/4
    int rem = idx - i * 192;
    int m   = rem >> 6;
    int d4  = rem & 63;
    ushort4 o;
    o.x = f2bf(v.x); o.y = f2bf(v.y); o.z = f2bf(v.z); o.w = f2bf(v.w);
    reinterpret_cast<ushort4*>(out)[((size_t)m * B_N + i) * 64 + d4] = o;
    float nx = bf2f(o.x), ny = bf2f(o.y), nz = bf2f(o.z), nw = bf2f(o.w);
    float s = nx * nx + ny * ny + nz * nz + nw * nw;
#pragma unroll
    for (int msk = 1; msk < 64; msk <<= 1) s += __shfl_xor(s, msk);
    if ((threadIdx.x & 63) == 0) norm2[m * B_N + i] = s;  // wave spans one (i,m) row
}

// Block: 128 rows x 512 cols; 4 waves x 32 rows (r4-proven geometry).
// TRIPLE-buffered LDS B tiles: tile p+1 is fully staged one barrier before
// phase p+1, so its fragments are ds_read during phase p (hidden under the
// epilogue) -> zero post-barrier LDS latency at each phase start.
// grid = 3m x 8ns x 32rb = 768 blocks. launch_bounds(256,2): VGPR ~190, NO spill.
__global__ __launch_bounds__(256, 2) void main_kernel(
    const unsigned short* __restrict__ tokb, const int* __restrict__ labels,
    float2* __restrict__ partials) {
    int raw = blockIdx.x;
    int bid = (raw & 7) * 96 + (raw >> 3);   // bijective XCD swizzle (768 % 8 == 0)
    int m  = bid >> 8;
    int ns = (bid >> 5) & 7;
    int rb = bid & 31;
    int i0 = rb * 128;
    int cb = ns * 512;

    int tid  = threadIdx.x;
    int wave = tid >> 6, lane = tid & 63;
    int lr = lane & 15, lk = lane >> 4;
    const unsigned short* tm = tokb + (size_t)m * (B_N * D_N);

    __shared__ __align__(16) char ldsB[3][8192];
    __shared__ int labl[512];
    labl[tid]       = labels[cb + tid];
    labl[tid + 256] = labels[cb + tid + 256];

    int r0 = i0 + wave * 32;
    bf16x8 afrag[2][8];
#pragma unroll
    for (int rt = 0; rt < 2; ++rt) {
        const unsigned short* rp = tm + (size_t)(r0 + rt * 16 + lr) * D_N + lk * 8;
#pragma unroll
        for (int kf = 0; kf < 8; ++kf)
            afrag[rt][kf] = *reinterpret_cast<const bf16x8*>(rp + kf * 32);
    }
    int labr[2][4];
#pragma unroll
    for (int rt = 0; rt < 2; ++rt)
#pragma unroll
        for (int j = 0; j < 4; ++j)
            labr[rt][j] = labels[r0 + rt * 16 + lk * 4 + j];

    float S[2][4] = {{0.f, 0.f, 0.f, 0.f}, {0.f, 0.f, 0.f, 0.f}};
    float P[2][4] = {{0.f, 0.f, 0.f, 0.f}, {0.f, 0.f, 0.f, 0.f}};

    // Staging map (verified r4-r11): thread (lc = tid>>5, w = tid&31) loads
    // source chunk sch = w ^ (lc&7) of cols (cb+lc),(cb+lc+8); writes LDS
    // linearly at tid*16 / 4096+tid*16. Reads apply the same XOR.
    int lc  = tid >> 5;
    int w   = tid & 31;
    int sch = w ^ (lc & 7);
    const unsigned short* sbase = tm + (size_t)(cb + lc) * D_N + sch * 8;
    int swz = (lr & 7) << 4;

    // prologue: stage tiles 0 -> buf0 and 1 -> buf1
    {
        bf16x8 a0 = *reinterpret_cast<const bf16x8*>(sbase);
        bf16x8 a1 = *reinterpret_cast<const bf16x8*>(sbase + 8 * D_N);
        bf16x8 b0 = *reinterpret_cast<const bf16x8*>(sbase + 16 * D_N);
        bf16x8 b1 = *reinterpret_cast<const bf16x8*>(sbase + 24 * D_N);
        *reinterpret_cast<bf16x8*>(&ldsB[0][tid * 16])        = a0;
        *reinterpret_cast<bf16x8*>(&ldsB[0][4096 + tid * 16]) = a1;
        *reinterpret_cast<bf16x8*>(&ldsB[1][tid * 16])        = b0;
        *reinterpret_cast<bf16x8*>(&ldsB[1][4096 + tid * 16]) = b1;
    }
    __syncthreads();

    char* pc = ldsB[0];   // current tile buffer
    char* pn = ldsB[1];   // next tile buffer (already staged)
    char* ps = ldsB[2];   // staging target (tile kb+2)

    bf16x8 bfA[8], bfB[8];
#pragma unroll
    for (int kf = 0; kf < 8; ++kf)
        bfA[kf] = *reinterpret_cast<const bf16x8*>(pc + lr * 512 + (((kf * 4 + lk) << 4) ^ swz));

#define PHASE(KB, BFC, BFN)                                                          \
    {                                                                                \
        int kb_ = (KB);                                                              \
        bf16x8 nt0, nt1;                                                             \
        if (kb_ < 30) { /* global loads for tile kb+2 (early issue) */               \
            const unsigned short* np = sbase + (size_t)(kb_ + 2) * (16 * D_N);       \
            nt0 = *reinterpret_cast<const bf16x8*>(np);                              \
            nt1 = *reinterpret_cast<const bf16x8*>(np + 8 * D_N);                    \
        }                                                                            \
        f32x4 acc0 = {0.f, 0.f, 0.f, 0.f};                                           \
        f32x4 acc1 = {0.f, 0.f, 0.f, 0.f};                                           \
        _Pragma("unroll")                                                            \
        for (int kf = 0; kf < 8; ++kf) {                                             \
            acc0 = __builtin_amdgcn_mfma_f32_16x16x32_bf16(afrag[0][kf], BFC[kf],    \
                                                           acc0, 0, 0, 0);           \
            acc1 = __builtin_amdgcn_mfma_f32_16x16x32_bf16(afrag[1][kf], BFC[kf],    \
                                                           acc1, 0, 0, 0);           \
        }                                                                            \
        if (kb_ < 31) { /* prefetch NEXT tile's fragments (staged last phase) */     \
            _Pragma("unroll")                                                        \
            for (int kf = 0; kf < 8; ++kf)                                           \
                BFN[kf] = *reinterpret_cast<const bf16x8*>(                          \
                    pn + lr * 512 + (((kf * 4 + lk) << 4) ^ swz));                   \
        }                                                                            \
        int labc = labl[kb_ * 16 + lr];                                              \
        int cg0 = cb + kb_ * 16;                                                     \
        if ((cg0 < r0 + 32) && (cg0 + 16 > r0)) {                                    \
            int colg = cg0 + lr;                                                     \
            _Pragma("unroll")                                                        \
            for (int rt = 0; rt < 2; ++rt) {                                         \
                f32x4 aa = rt ? acc1 : acc0;                                         \
                _Pragma("unroll")                                                    \
                for (int j = 0; j < 4; ++j) {                                        \
                    float s2 = aa[j];                                                \
                    float t = fminf(fmaf(s2, LOG2E, -C_OFF), T_CLAMP);                \
                    float e = __builtin_amdgcn_exp2f(t);                             \
                    int row = r0 + rt * 16 + lk * 4 + j;                             \
                    e = (colg == row) ? 0.f : e;                                     \
                    S[rt][j] += e;                                                   \
                    P[rt][j] += (labc == labr[rt][j]) ? s2 : 0.f;                    \
                }                                                                    \
            }                                                                        \
        } else {                                                                     \
            _Pragma("unroll")                                                        \
            for (int rt = 0; rt < 2; ++rt) {                                         \
                f32x4 aa = rt ? acc1 : acc0;                                         \
                _Pragma("unroll")                                                    \
                for (int j = 0; j < 4; ++j) {                                        \
                    float s2 = aa[j];                                                \
                    float t = fminf(fmaf(s2, LOG2E, -C_OFF), T_CLAMP);                \
                    S[rt][j] += __builtin_amdgcn_exp2f(t);                           \
                    P[rt][j] += (labc == labr[rt][j]) ? s2 : 0.f;                    \
                }                                                                    \
            }                                                                        \
        }                                                                            \
        if (kb_ < 30) { /* stage tile kb+2 */                                        \
            *reinterpret_cast<bf16x8*>(ps + tid * 16)        = nt0;                  \
            *reinterpret_cast<bf16x8*>(ps + 4096 + tid * 16) = nt1;                  \
        }                                                                            \
        __syncthreads();                                                             \
        char* tmp_ = pc; pc = pn; pn = ps; ps = tmp_;                                \
    }

    for (int it = 0; it < 16; ++it) {
        PHASE(2 * it,     bfA, bfB);
        PHASE(2 * it + 1, bfB, bfA);
    }
#undef PHASE

    // sum across the 16 col-lanes (lanes sharing lk hold the same rows)
#pragma unroll
    for (int rt = 0; rt < 2; ++rt)
#pragma unroll
        for (int j = 0; j < 4; ++j) {
            float sv = S[rt][j], pv = P[rt][j];
#pragma unroll
            for (int msk = 1; msk < 16; msk <<= 1) {
                sv += __shfl_xor(sv, msk);
                pv += __shfl_xor(pv, msk);
            }
            if (lr == 0) {
                int rl = rt * 16 + lk * 4 + j;
                float2 q; q.x = sv; q.y = pv;
                partials[(size_t)(((m * 32 + rb) * 8 + ns) * 128) + wave * 32 + rl] = q;
            }
        }
}

// one thread per (m,i): merge 8 col-split partials, finish the loss term.
// Histogram built in-block; block 0 publishes nv for final_kernel. (r6-proven)
__global__ void reduce_kernel(const float2* __restrict__ partials,
                              const float* __restrict__ norm2,
                              const int* __restrict__ labels,
                              float* __restrict__ blockpart,
                              int* __restrict__ nvout) {
    __shared__ int h[32];
    int tid = threadIdx.x;
    if (tid < 32) h[tid] = 0;
    __syncthreads();
    for (int i = tid; i < B_N; i += 256) atomicAdd(&h[labels[i]], 1);
    __syncthreads();
    if (blockIdx.x == 0 && tid == 0) {
        int nv = 0;
#pragma unroll
        for (int c = 0; c < 32; ++c) nv += (h[c] >= 2) ? h[c] : 0;
        nvout[0] = nv;
    }
    int gid = blockIdx.x * 256 + tid;   // 12288
    int m = gid >> 12, i = gid & 4095;
    int rb = i >> 7, r = i & 127;
    const float2* pp = partials + (size_t)(((m * 32 + rb) * 8) * 128) + r;
    float S = 0.f, P = 0.f;
#pragma unroll
    for (int ns = 0; ns < 8; ++ns) {
        float2 q = pp[ns * 128];
        S += q.x; P += q.y;
    }
    P -= norm2[gid];                       // remove self-sim from positive sum
    int pc = h[labels[i]] - 1;
    float contrib = (pc > 0)
        ? (__builtin_amdgcn_logf(S) + C_OFF) * LN2 - P / (float)pc
        : 0.f;
#pragma unroll
    for (int off = 32; off >= 1; off >>= 1) contrib += __shfl_down(contrib, off);
    __shared__ float w4[4];
    if ((tid & 63) == 0) w4[tid >> 6] = contrib;
    __syncthreads();
    if (tid == 0) blockpart[blockIdx.x] = w4[0] + w4[1] + w4[2] + w4[3];
}

__global__ void final_kernel(const float* __restrict__ blockpart, const int* __restrict__ nv,
                             float* __restrict__ out) {
    int lane = threadIdx.x;
    float s = (lane < 48) ? blockpart[lane] : 0.f;
#pragma unroll
    for (int off = 32; off >= 1; off >>= 1) s += __shfl_down(s, off);
    if (lane == 0) out[0] = s / (float)(nv[0] * M_N);
}

extern "C" void kernel_launch(void* const* d_in, const int* in_sizes, int n_in,
                              void* d_out, int out_size, void* d_ws, size_t ws_size,
                              hipStream_t stream) {
    const float* tokens = (const float*)d_in[0];
    const int*   labels = (const int*)d_in[1];
    float* out = (float*)d_out;

    char* ws = (char*)d_ws;
    int*    nv        = (int*)(ws + 128);                   // 1 int
    float*  blockpart = (float*)(ws + 256);                 // 48 floats
    float*  norm2     = (float*)(ws + 1024);                // 12288 floats
    float2* partials  = (float2*)(ws + 65536);              // 768*128 float2 = 786 KB
    unsigned short* tokb = (unsigned short*)(ws + 1048576); // 6.29 MB

    cvt_kernel<<<3072, 256, 0, stream>>>(tokens, tokb, norm2);
    main_kernel<<<768, 256, 0, stream>>>(tokb, labels, partials);
    reduce_kernel<<<48, 256, 0, stream>>>(partials, norm2, labels, blockpart, nv);
    final_kernel<<<1, 64, 0, stream>>>(blockpart, nv, out);
}

// Round 13
// 51.249 us; speedup vs baseline: 2.3360x; 1.0710x over previous
//
#include <hip/hip_runtime.h>

#define B_N 4096
#define M_N 3
#define D_N 256
#define LOG2E 1.44269504088896340736f
#define LN2   0.69314718055994530942f
#define C_OFF   64.0f
#define T_CLAMP 112.0f

typedef __bf16 bf16x8 __attribute__((ext_vector_type(8)));
typedef float  f32x4  __attribute__((ext_vector_type(4)));

__device__ __forceinline__ unsigned short f2bf(float f) {
    unsigned int u = __float_as_uint(f);
    u += 0x7FFFu + ((u >> 16) & 1u);   // round-to-nearest-even
    return (unsigned short)(u >> 16);
}
__device__ __forceinline__ float bf2f(unsigned short h) {
    return __uint_as_float(((unsigned int)h) << 16);
}

// tokens [i][m][d] f32 -> tokb [m][i][d] bf16; norm2[m*B+i] = sum(bf16(x)^2)
__global__ void cvt_kernel(const float* __restrict__ in, unsigned short* __restrict__ out,
                           float* __restrict__ norm2) {
    int idx = blockIdx.x * blockDim.x + threadIdx.x;   // 786432 float4s
    float4 v = reinterpret_cast<const float4*>(in)[idx];
    int i   = idx / 192;            // 192 = M*D/4
    int rem = idx - i * 192;
    int m   = rem >> 6;
    int d4  = rem & 63;
    ushort4 o;
    o.x = f2bf(v.x); o.y = f2bf(v.y); o.z = f2bf(v.z); o.w = f2bf(v.w);
    reinterpret_cast<ushort4*>(out)[((size_t)m * B_N + i) * 64 + d4] = o;
    float nx = bf2f(o.x), ny = bf2f(o.y), nz = bf2f(o.z), nw = bf2f(o.w);
    float s = nx * nx + ny * ny + nz * nz + nw * nw;
#pragma unroll
    for (int msk = 1; msk < 64; msk <<= 1) s += __shfl_xor(s, msk);
    if ((threadIdx.x & 63) == 0) norm2[m * B_N + i] = s;  // wave spans one (i,m) row
}

// ===== main kernel: byte-identical to the round-4 measured 43.0 µs form =====
// Block: 128 rows x 512 cols of one modality; 4 waves x 32 rows.
// B tile (16 cols x 256 d = 8 KB) shared across waves via LDS, double-buffered.
// Staging: global->reg->ds_write (linear, conflict-free), XOR-swizzled chunk
// placement; ds_read_b128 applies the same XOR -> ~2-way (free) on reads.
// grid = 3m x 8ns x 32rb = 768 blocks, 3 blocks/CU co-resident.
__global__ __launch_bounds__(256, 3) void main_kernel(
    const unsigned short* __restrict__ tokb, const int* __restrict__ labels,
    float2* __restrict__ partials) {
    int raw = blockIdx.x;
    int bid = (raw & 7) * 96 + (raw >> 3);   // bijective XCD swizzle (768 % 8 == 0)
    int m  = bid >> 8;
    int ns = (bid >> 5) & 7;
    int rb = bid & 31;
    int i0 = rb * 128;
    int cb = ns * 512;

    int tid  = threadIdx.x;
    int wave = tid >> 6, lane = tid & 63;
    int lr = lane & 15, lk = lane >> 4;
    const unsigned short* tm = tokb + (size_t)m * (B_N * D_N);

    __shared__ __align__(16) char ldsB[2][8192];
    __shared__ int labl[512];
    labl[tid]       = labels[cb + tid];
    labl[tid + 256] = labels[cb + tid + 256];

    // A fragments: rows r0 + rt*16 + lr, registers for whole kernel
    int r0 = i0 + wave * 32;
    bf16x8 afrag[2][8];
#pragma unroll
    for (int rt = 0; rt < 2; ++rt) {
        const unsigned short* rp = tm + (size_t)(r0 + rt * 16 + lr) * D_N + lk * 8;
#pragma unroll
        for (int kf = 0; kf < 8; ++kf)
            afrag[rt][kf] = *reinterpret_cast<const bf16x8*>(rp + kf * 32);
    }
    int labr[2][4];
#pragma unroll
    for (int rt = 0; rt < 2; ++rt)
#pragma unroll
        for (int j = 0; j < 4; ++j)
            labr[rt][j] = labels[r0 + rt * 16 + lk * 4 + j];

    float S[2][4] = {{0.f, 0.f, 0.f, 0.f}, {0.f, 0.f, 0.f, 0.f}};
    float P[2][4] = {{0.f, 0.f, 0.f, 0.f}, {0.f, 0.f, 0.f, 0.f}};

    // Staging map: thread (lc = tid>>5 in 0..7, w = tid&31) loads source chunk
    // sch = w ^ (lc&7) of cols (cb+lc) and (cb+lc+8), writes LDS linearly at
    // tid*16 and 4096+tid*16.  => LDS[col*512 + w*16] = global[col][w ^ (col&7)]
    int lc  = tid >> 5;
    int w   = tid & 31;
    int sch = w ^ (lc & 7);
    const unsigned short* sbase = tm + (size_t)(cb + lc) * D_N + sch * 8;

    // prologue: tile 0 -> regs -> buf 0
    {
        bf16x8 t0 = *reinterpret_cast<const bf16x8*>(sbase);
        bf16x8 t1 = *reinterpret_cast<const bf16x8*>(sbase + 8 * D_N);
        *reinterpret_cast<bf16x8*>(&ldsB[0][tid * 16])        = t0;
        *reinterpret_cast<bf16x8*>(&ldsB[0][4096 + tid * 16]) = t1;
    }

    for (int kb = 0; kb < 32; ++kb) {
        int cur = kb & 1;
        __syncthreads();   // buf[cur] staged; all reads of buf[cur^1] drained

        // issue next-tile global loads early (latency hides under compute)
        int nkb = (kb + 1) & 31;   // wrap: last-iter load/write is dead but safe
        const unsigned short* np = sbase + (size_t)nkb * (16 * D_N);
        bf16x8 nt0 = *reinterpret_cast<const bf16x8*>(np);
        bf16x8 nt1 = *reinterpret_cast<const bf16x8*>(np + 8 * D_N);

        const char* bp = ldsB[cur];
        int swz = (lr & 7) << 4;
        bf16x8 bfrag[8];
#pragma unroll
        for (int kf = 0; kf < 8; ++kf)
            bfrag[kf] = *reinterpret_cast<const bf16x8*>(
                bp + lr * 512 + ((((kf * 4 + lk) << 4)) ^ swz));
        int labc = labl[kb * 16 + lr];

        f32x4 acc0 = {0.f, 0.f, 0.f, 0.f};
        f32x4 acc1 = {0.f, 0.f, 0.f, 0.f};
#pragma unroll
        for (int kf = 0; kf < 8; ++kf) {
            acc0 = __builtin_amdgcn_mfma_f32_16x16x32_bf16(afrag[0][kf], bfrag[kf], acc0, 0, 0, 0);
            acc1 = __builtin_amdgcn_mfma_f32_16x16x32_bf16(afrag[1][kf], bfrag[kf], acc1, 0, 0, 0);
        }

        int cg0 = cb + kb * 16;
        if ((cg0 < r0 + 32) && (cg0 + 16 > r0)) {
            int colg = cg0 + lr;
#pragma unroll
            for (int rt = 0; rt < 2; ++rt) {
                f32x4 aa = rt ? acc1 : acc0;
#pragma unroll
                for (int j = 0; j < 4; ++j) {
                    float s = aa[j];
                    float t = fminf(fmaf(s, LOG2E, -C_OFF), T_CLAMP);
                    float e = __builtin_amdgcn_exp2f(t);
                    int row = r0 + rt * 16 + lk * 4 + j;
                    e = (colg == row) ? 0.f : e;   // exclude self from partition
                    S[rt][j] += e;
                    P[rt][j] += (labc == labr[rt][j]) ? s : 0.f;  // diag in, -norm2 later
                }
            }
        } else {
#pragma unroll
            for (int rt = 0; rt < 2; ++rt) {
                f32x4 aa = rt ? acc1 : acc0;
#pragma unroll
                for (int j = 0; j < 4; ++j) {
                    float s = aa[j];
                    float t = fminf(fmaf(s, LOG2E, -C_OFF), T_CLAMP);
                    S[rt][j] += __builtin_amdgcn_exp2f(t);
                    P[rt][j] += (labc == labr[rt][j]) ? s : 0.f;
                }
            }
        }

        // write next tile (other buffer); barrier at loop top publishes it
        char* dst = (char*)ldsB[cur ^ 1];
        *reinterpret_cast<bf16x8*>(dst + tid * 16)        = nt0;
        *reinterpret_cast<bf16x8*>(dst + 4096 + tid * 16) = nt1;
    }

    // sum across the 16 col-lanes (lanes sharing lk hold the same rows)
#pragma unroll
    for (int rt = 0; rt < 2; ++rt)
#pragma unroll
        for (int j = 0; j < 4; ++j) {
            float sv = S[rt][j], pv = P[rt][j];
#pragma unroll
            for (int msk = 1; msk < 16; msk <<= 1) {
                sv += __shfl_xor(sv, msk);
                pv += __shfl_xor(pv, msk);
            }
            if (lr == 0) {
                int rl = rt * 16 + lk * 4 + j;
                float2 q; q.x = sv; q.y = pv;
                partials[(size_t)(((m * 32 + rb) * 8 + ns) * 128) + wave * 32 + rl] = q;
            }
        }
}

// one thread per (m,i): merge 8 col-split partials, finish the loss term.
// Histogram built in-block; block 0 publishes nv for final_kernel. (r6-proven)
__global__ void reduce_kernel(const float2* __restrict__ partials,
                              const float* __restrict__ norm2,
                              const int* __restrict__ labels,
                              float* __restrict__ blockpart,
                              int* __restrict__ nvout) {
    __shared__ int h[32];
    int tid = threadIdx.x;
    if (tid < 32) h[tid] = 0;
    __syncthreads();
    for (int i = tid; i < B_N; i += 256) atomicAdd(&h[labels[i]], 1);
    __syncthreads();
    if (blockIdx.x == 0 && tid == 0) {
        int nv = 0;
#pragma unroll
        for (int c = 0; c < 32; ++c) nv += (h[c] >= 2) ? h[c] : 0;
        nvout[0] = nv;
    }
    int gid = blockIdx.x * 256 + tid;   // 12288
    int m = gid >> 12, i = gid & 4095;
    int rb = i >> 7, r = i & 127;
    const float2* pp = partials + (size_t)(((m * 32 + rb) * 8) * 128) + r;
    float S = 0.f, P = 0.f;
#pragma unroll
    for (int ns = 0; ns < 8; ++ns) {
        float2 q = pp[ns * 128];
        S += q.x; P += q.y;
    }
    P -= norm2[gid];                       // remove self-sim from positive sum
    int pc = h[labels[i]] - 1;
    float contrib = (pc > 0)
        ? (__builtin_amdgcn_logf(S) + C_OFF) * LN2 - P / (float)pc
        : 0.f;
#pragma unroll
    for (int off = 32; off >= 1; off >>= 1) contrib += __shfl_down(contrib, off);
    __shared__ float w4[4];
    if ((tid & 63) == 0) w4[tid >> 6] = contrib;
    __syncthreads();
    if (tid == 0) blockpart[blockIdx.x] = w4[0] + w4[1] + w4[2] + w4[3];
}

__global__ void final_kernel(const float* __restrict__ blockpart, const int* __restrict__ nv,
                             float* __restrict__ out) {
    int lane = threadIdx.x;
    float s = (lane < 48) ? blockpart[lane] : 0.f;
#pragma unroll
    for (int off = 32; off >= 1; off >>= 1) s += __shfl_down(s, off);
    if (lane == 0) out[0] = s / (float)(nv[0] * M_N);
}

extern "C" void kernel_launch(void* const* d_in, const int* in_sizes, int n_in,
                              void* d_out, int out_size, void* d_ws, size_t ws_size,
                              hipStream_t stream) {
    const float* tokens = (const float*)d_in[0];
    const int*   labels = (const int*)d_in[1];
    float* out = (float*)d_out;

    char* ws = (char*)d_ws;
    int*    nv        = (int*)(ws + 128);                   // 1 int
    float*  blockpart = (float*)(ws + 256);                 // 48 floats
    float*  norm2     = (float*)(ws + 1024);                // 12288 floats
    float2* partials  = (float2*)(ws + 65536);              // 768*128 float2 = 786 KB
    unsigned short* tokb = (unsigned short*)(ws + 1048576); // 6.29 MB

    cvt_kernel<<<3072, 256, 0, stream>>>(tokens, tokb, norm2);
    main_kernel<<<768, 256, 0, stream>>>(tokb, labels, partials);
    reduce_kernel<<<48, 256, 0, stream>>>(partials, norm2, labels, blockpart, nv);
    final_kernel<<<1, 64, 0, stream>>>(blockpart, nv, out);
}